// Round 13
// baseline (539.022 us; speedup 1.0000x reference)
//
#include <hip/hip_runtime.h>
#include <hip/hip_bf16.h>

#define RFn 500000
#define F1n 256
#define NFn 128
#define RAn 50000
#define LN_EPSn 1e-5f
#define SPW 5                          // segments per wave (fused kernel)
#define NWV ((RAn + SPW - 1) / SPW)    // 10000 waves
#define NBLK2 ((NWV + 3) / 4)          // 2500 blocks of 4 waves
#define SCB 256
#define SCG ((RAn + SCB - 1) / SCB)    // 196

typedef float f32x4 __attribute__((ext_vector_type(4)));
typedef short short8 __attribute__((ext_vector_type(8)));

__device__ __forceinline__ short f2bf(float f) {
  __hip_bfloat16 h = __float2bfloat16(f);  // RNE
  return __builtin_bit_cast(short, h);
}

// ---------------------------------------------------------------------------
// Pack W_feat (256x128 f32) into MFMA frag image: frag (s,c), lane l holds
// W[k=s*32+(l>>4)*8+i][col=c*16+(l&15)], i=0..7. Used as the A-operand in the
// swapped-operand MFMA (r6-verified layout).
// ---------------------------------------------------------------------------
__global__ void prep_kernel(const float* __restrict__ Wf, short* __restrict__ frag) {
  int p = blockIdx.x * blockDim.x + threadIdx.x;  // 0..4095
  if (p >= 4096) return;
  int f = p >> 6, l = p & 63;
  int s = f >> 3, c = f & 7;
  int col = c * 16 + (l & 15);
  int k0 = s * 32 + ((l >> 4) << 3);
  short8 v;
#pragma unroll
  for (int i = 0; i < 8; ++i) v[i] = f2bf(Wf[(k0 + i) * NFn + col]);
  *(short8*)(frag + (size_t)p * 8) = v;
}

__global__ void hist_kernel(const int* __restrict__ ri, int* __restrict__ hist) {
  int i = blockIdx.x * 256 + threadIdx.x;
  if (i < RFn) atomicAdd(&hist[ri[i]], 1);
}

__global__ __launch_bounds__(256) void scanA_kernel(const int* __restrict__ hist,
                                                    int* __restrict__ T,
                                                    int* __restrict__ bsum) {
  __shared__ int ls[256];
  const int t = threadIdx.x, idx = blockIdx.x * 256 + t;
  const int v = (idx < RAn) ? hist[idx] : 0;
  ls[t] = v;
  __syncthreads();
  for (int off = 1; off < 256; off <<= 1) {
    int add = (t >= off) ? ls[t - off] : 0;
    __syncthreads();
    ls[t] += add;
    __syncthreads();
  }
  if (idx < RAn) T[idx] = ls[t] - v;
  if (t == 255) bsum[blockIdx.x] = ls[255];
}

__global__ __launch_bounds__(256) void scanB_kernel(int* __restrict__ bsum,
                                                    int* __restrict__ boff) {
  __shared__ int ls[256];
  const int t = threadIdx.x;
  const int v = (t < SCG) ? bsum[t] : 0;
  ls[t] = v;
  __syncthreads();
  for (int off = 1; off < 256; off <<= 1) {
    int add = (t >= off) ? ls[t - off] : 0;
    __syncthreads();
    ls[t] += add;
    __syncthreads();
  }
  if (t < SCG) boff[t] = ls[t] - v;
}

__global__ __launch_bounds__(256) void scanC_kernel(const int* __restrict__ T,
                                                    const int* __restrict__ boff,
                                                    int* __restrict__ rowstart,
                                                    int* __restrict__ cursor) {
  const int idx = blockIdx.x * 256 + threadIdx.x;
  if (idx < RAn) {
    int v = T[idx] + boff[blockIdx.x];
    rowstart[idx] = v;
    cursor[idx] = v;
  }
  if (idx == 0) rowstart[RAn] = RFn;
}

// perm[pos] = original row (segment-major order)
__global__ void scatter_kernel(const int* __restrict__ ri, int* __restrict__ cursor,
                               int* __restrict__ perm) {
  int i = blockIdx.x * 256 + threadIdx.x;
  if (i < RFn) perm[atomicAdd(&cursor[ri[i]], 1)] = i;
}

// ---------------------------------------------------------------------------
// fused2: single pass, swapped-operand MFMA (r6 layout: lane owns row colb,
// cols c*16+kg*4+j -> low VGPR, high TLP). Each wave owns SPW consecutive
// segments (contiguous sorted rows via perm). Per 16-row tile: prefetched
// perm gather, GEMM, in-lane LN + logit/exp, then segmented accumulation:
// ballot run boundaries, masked shfl_xor(1,2,4,8) tree across colb lanes,
// coalesced 512B flush per finished segment. Segment ids from rowstart
// boundary compares (no sseg array). No atomics, no intermediate buffer,
// all register arrays statically indexed (rule #20).
// ---------------------------------------------------------------------------
__global__ __launch_bounds__(256) void fused2_kernel(
    const float* __restrict__ X, const short* __restrict__ fragWS,
    const float* __restrict__ Wa, const float* __restrict__ ba,
    const float* __restrict__ bfeat, const float* __restrict__ gamma,
    const float* __restrict__ beta, const int* __restrict__ rowstart,
    const int* __restrict__ perm, float* __restrict__ out) {
  __shared__ float sCoef[384];  // gamma[0:128] beta[128:256] bfeat[256:384]

  const int tid = threadIdx.x;
  if (tid < 128) {
    sCoef[tid] = gamma[tid];
    sCoef[128 + tid] = beta[tid];
    sCoef[256 + tid] = bfeat[tid];
  }
  __syncthreads();

  const int lane = tid & 63;
  const int wv = tid >> 6;
  const int colb = lane & 15;  // row-in-tile this lane owns
  const int kg = lane >> 4;    // column quarter

  const int wgid = blockIdx.x * 4 + wv;
  const int s0 = wgid * SPW;
  if (s0 >= RAn) return;
  const int s1 = min(s0 + SPW, RAn);
  const int rbeg = rowstart[s0];
  const int rend = rowstart[s1];
  if (rend <= rbeg) return;  // all empty: out stays 0 (memset)

  // interior segment boundaries (empty segments collapse correctly)
  const int b1 = rowstart[min(s0 + 1, s1)];
  const int b2 = rowstart[min(s0 + 2, s1)];
  const int b3 = rowstart[min(s0 + 3, s1)];
  const int b4 = rowstart[min(s0 + 4, s1)];

  const float batn = ba[0];

  f32x4 racc[8];
#pragma unroll
  for (int c = 0; c < 8; ++c) racc[c] = (f32x4)(0.0f);
  float wrun = 0.f;
  int curseg = -1;

  // prefetch first tile's row index
  int pcv = min(rbeg + colb, rend - 1);
  int rowv = perm[pcv];

  for (int base = rbeg; base < rend; base += 16) {
    const int n = min(16, rend - base);
    // prefetch next tile's perm entry (latency hidden under this tile)
    const int pcn = min(base + 16 + colb, rend - 1);
    const int rown = perm[pcn];

    // segment of this lane's row
    const int seg = s0 + (pcv >= b1) + (pcv >= b2) + (pcv >= b3) + (pcv >= b4);

    const float* xp = X + (size_t)rowv * F1n + kg * 8;

    // -------- GEMM over K=256 (swapped operands; B-frags from L2) --------
    f32x4 acc[8];
#pragma unroll
    for (int c = 0; c < 8; ++c) acc[c] = (f32x4)(0.0f);
    float logit = 0.f;

#pragma unroll
    for (int s = 0; s < 8; ++s) {
      short8 bfr[8];
#pragma unroll
      for (int c = 0; c < 8; ++c)
        bfr[c] = *(const short8*)(fragWS + (((s * 8 + c) * 64 + lane) * 8));
      const float4 wa0 = *(const float4*)(Wa + s * 32 + kg * 8);
      const float4 wa1 = *(const float4*)(Wa + s * 32 + kg * 8 + 4);
      const float4 x0 = *(const float4*)(xp + s * 32);
      const float4 x1 = *(const float4*)(xp + s * 32 + 4);
      float a0 = fmaxf(x0.x, 0.01f * x0.x);
      float a1 = fmaxf(x0.y, 0.01f * x0.y);
      float a2 = fmaxf(x0.z, 0.01f * x0.z);
      float a3 = fmaxf(x0.w, 0.01f * x0.w);
      float a4 = fmaxf(x1.x, 0.01f * x1.x);
      float a5 = fmaxf(x1.y, 0.01f * x1.y);
      float a6 = fmaxf(x1.z, 0.01f * x1.z);
      float a7 = fmaxf(x1.w, 0.01f * x1.w);
      logit += a0 * wa0.x + a1 * wa0.y + a2 * wa0.z + a3 * wa0.w +
               a4 * wa1.x + a5 * wa1.y + a6 * wa1.z + a7 * wa1.w;
      short8 af;
      af[0] = f2bf(a0); af[1] = f2bf(a1); af[2] = f2bf(a2); af[3] = f2bf(a3);
      af[4] = f2bf(a4); af[5] = f2bf(a5); af[6] = f2bf(a6); af[7] = f2bf(a7);
#pragma unroll
      for (int c = 0; c < 8; ++c)  // SWAPPED: W as A, X as B (r6-verified)
        acc[c] = __builtin_amdgcn_mfma_f32_16x16x32_bf16(bfr[c], af, acc[c], 0, 0, 0);
    }

    // -------- logit -> w (row colb; reduce across kg lanes) --------
    float lg = logit;
    lg += __shfl_xor(lg, 16);
    lg += __shfl_xor(lg, 32);
    const float wexp = __expf(lg + batn);

    // -------- bias + LN (in-lane 32 vals + kg tree), then *wexp --------
    float s1v = 0.f, s2v = 0.f;
#pragma unroll
    for (int c = 0; c < 8; ++c) {
      const f32x4 bi = *(const f32x4*)&sCoef[256 + c * 16 + kg * 4];
#pragma unroll
      for (int j = 0; j < 4; ++j) {
        float v = acc[c][j] + bi[j];
        acc[c][j] = v;
        s1v += v;
        s2v += v * v;
      }
    }
    s1v += __shfl_xor(s1v, 16);
    s1v += __shfl_xor(s1v, 32);
    s2v += __shfl_xor(s2v, 16);
    s2v += __shfl_xor(s2v, 32);
    const float mu = s1v * (1.0f / NFn);
    const float var = s2v * (1.0f / NFn) - mu * mu;
    const float rs = rsqrtf(var + LN_EPSn);
#pragma unroll
    for (int c = 0; c < 8; ++c) {
      const f32x4 gg = *(const f32x4*)&sCoef[c * 16 + kg * 4];
      const f32x4 bb = *(const f32x4*)&sCoef[128 + c * 16 + kg * 4];
#pragma unroll
      for (int j = 0; j < 4; ++j)
        acc[c][j] = ((acc[c][j] - mu) * rs * gg[j] + bb[j]) * wexp;
    }

    // -------- segmented accumulation over the n rows of this tile --------
    const int segp = __shfl(seg, (lane - 1) & 63);  // colb-1 (same kg); unused at colb==0
    unsigned long long bm =
        __ballot(colb < n && (colb == 0 || seg != segp)) & 0xFFFFull;

    int a = 0;
    while (a < n) {
      unsigned long long rest = (a + 1 < 16) ? (bm >> (a + 1)) : 0ull;
      const int b = rest ? (a + 1 + (int)__builtin_ctzll(rest)) : n;
      const int rseg = __shfl(seg, a);

      const bool in = (colb >= a) && (colb < b);
      float wc = in ? wexp : 0.f;
      f32x4 con[8];
#pragma unroll
      for (int c = 0; c < 8; ++c) con[c] = in ? acc[c] : (f32x4)(0.0f);
#pragma unroll
      for (int off = 1; off <= 8; off <<= 1) {
        wc += __shfl_xor(wc, off);
#pragma unroll
        for (int c = 0; c < 8; ++c)
#pragma unroll
          for (int j = 0; j < 4; ++j) con[c][j] += __shfl_xor(con[c][j], off);
      }

      if (rseg != curseg) {
        if (curseg >= 0) {  // coalesced 512B flush; static racc indexing
          const float iw = 1.0f / wrun;
          f32x4 val = racc[0];
#pragma unroll
          for (int c = 1; c < 8; ++c)
            if (colb == c) val = racc[c];
          if (colb < 8) {
            f32x4 o;
#pragma unroll
            for (int j = 0; j < 4; ++j) o[j] = val[j] * iw;
            *(f32x4*)(out + (size_t)curseg * NFn + colb * 16 + kg * 4) = o;
          }
        }
        curseg = rseg;
#pragma unroll
        for (int c = 0; c < 8; ++c) racc[c] = con[c];
        wrun = wc;
      } else {
#pragma unroll
        for (int c = 0; c < 8; ++c)
#pragma unroll
          for (int j = 0; j < 4; ++j) racc[c][j] += con[c][j];
        wrun += wc;
      }
      a = b;
    }

    pcv = pcn;
    rowv = rown;
  }

  // final flush
  if (curseg >= 0) {
    const float iw = 1.0f / wrun;
    f32x4 val = racc[0];
#pragma unroll
    for (int c = 1; c < 8; ++c)
      if (colb == c) val = racc[c];
    if (colb < 8) {
      f32x4 o;
#pragma unroll
      for (int j = 0; j < 4; ++j) o[j] = val[j] * iw;
      *(f32x4*)(out + (size_t)curseg * NFn + colb * 16 + kg * 4) = o;
    }
  }
}

// ---------------------------------------------------------------------------
// Fallback path (small ws): round-1 atomic kernel, known-good.
// ---------------------------------------------------------------------------
__global__ __launch_bounds__(256) void main_atomic(
    const float* __restrict__ X, const short* __restrict__ fragWS,
    const float* __restrict__ Wa, const float* __restrict__ ba,
    const float* __restrict__ bfeat, const float* __restrict__ gamma,
    const float* __restrict__ beta, const int* __restrict__ res_index,
    float* __restrict__ Nacc, float* __restrict__ D) {
  __shared__ short sB[4096 * 8];
  const int tid = threadIdx.x;
  {
    const int4* src = (const int4*)fragWS;
    int4* dst = (int4*)sB;
#pragma unroll 4
    for (int i = tid; i < 4096; i += 256) dst[i] = src[i];
  }
  __syncthreads();
  const int lane = tid & 63;
  const int wv = tid >> 6;
  const int rowbase = blockIdx.x * 128 + wv * 32;
  const int colb = lane & 15;
  const int kg = lane >> 4;
  float g_r[8], be_r[8], bi_r[8];
#pragma unroll
  for (int c = 0; c < 8; ++c) {
    int col = c * 16 + colb;
    g_r[c] = gamma[col];
    be_r[c] = beta[col];
    bi_r[c] = bfeat[col];
  }
  const float batn = ba[0];
  f32x4 acc[2][8];
#pragma unroll
  for (int rt = 0; rt < 2; ++rt)
#pragma unroll
    for (int c = 0; c < 8; ++c) acc[rt][c] = (f32x4)(0.0f);
  float logit[2] = {0.f, 0.f};
  int gr0 = rowbase + colb;
  int gr1 = gr0 + 16;
  long r0 = (gr0 < RFn) ? gr0 : (RFn - 1);
  long r1 = (gr1 < RFn) ? gr1 : (RFn - 1);
  const float* xp0 = X + r0 * F1n + kg * 8;
  const float* xp1 = X + r1 * F1n + kg * 8;
#pragma unroll
  for (int s = 0; s < 8; ++s) {
    short8 bfr[8];
#pragma unroll
    for (int c = 0; c < 8; ++c)
      bfr[c] = *(const short8*)(sB + (((s * 8 + c) * 64 + lane) * 8));
    const float4 wa0 = *(const float4*)(Wa + s * 32 + kg * 8);
    const float4 wa1 = *(const float4*)(Wa + s * 32 + kg * 8 + 4);
#pragma unroll
    for (int rt = 0; rt < 2; ++rt) {
      const float* xp = rt ? xp1 : xp0;
      const float4 x0 = *(const float4*)(xp + s * 32);
      const float4 x1 = *(const float4*)(xp + s * 32 + 4);
      float a0 = fmaxf(x0.x, 0.01f * x0.x);
      float a1 = fmaxf(x0.y, 0.01f * x0.y);
      float a2 = fmaxf(x0.z, 0.01f * x0.z);
      float a3 = fmaxf(x0.w, 0.01f * x0.w);
      float a4 = fmaxf(x1.x, 0.01f * x1.x);
      float a5 = fmaxf(x1.y, 0.01f * x1.y);
      float a6 = fmaxf(x1.z, 0.01f * x1.z);
      float a7 = fmaxf(x1.w, 0.01f * x1.w);
      logit[rt] += a0 * wa0.x + a1 * wa0.y + a2 * wa0.z + a3 * wa0.w +
                   a4 * wa1.x + a5 * wa1.y + a6 * wa1.z + a7 * wa1.w;
      short8 af;
      af[0] = f2bf(a0); af[1] = f2bf(a1); af[2] = f2bf(a2); af[3] = f2bf(a3);
      af[4] = f2bf(a4); af[5] = f2bf(a5); af[6] = f2bf(a6); af[7] = f2bf(a7);
#pragma unroll
      for (int c = 0; c < 8; ++c)
        acc[rt][c] = __builtin_amdgcn_mfma_f32_16x16x32_bf16(af, bfr[c],
                                                             acc[rt][c], 0, 0, 0);
    }
  }
#pragma unroll
  for (int rt = 0; rt < 2; ++rt) {
    float lg = logit[rt];
    lg += __shfl_xor(lg, 16);
    lg += __shfl_xor(lg, 32);
    const float wexp = __expf(lg + batn);
    const int gr = rowbase + rt * 16 + colb;
    const int seg = res_index[(gr < RFn) ? gr : (RFn - 1)];
    if (lane < 16 && gr < RFn) atomicAdd(&D[seg], wexp);
    float w4[4];
    int s4[4], v4[4];
#pragma unroll
    for (int reg = 0; reg < 4; ++reg) {
      int srcl = kg * 4 + reg;
      w4[reg] = __shfl(wexp, srcl);
      s4[reg] = __shfl(seg, srcl);
      v4[reg] = (rowbase + rt * 16 + srcl) < RFn;
    }
    float s1v[4] = {0.f, 0.f, 0.f, 0.f}, s2v[4] = {0.f, 0.f, 0.f, 0.f};
#pragma unroll
    for (int c = 0; c < 8; ++c)
#pragma unroll
      for (int reg = 0; reg < 4; ++reg) {
        float t2 = acc[rt][c][reg] + bi_r[c];
        acc[rt][c][reg] = t2;
        s1v[reg] += t2;
        s2v[reg] += t2 * t2;
      }
#pragma unroll
    for (int off = 1; off <= 8; off <<= 1)
#pragma unroll
      for (int reg = 0; reg < 4; ++reg) {
        s1v[reg] += __shfl_xor(s1v[reg], off);
        s2v[reg] += __shfl_xor(s2v[reg], off);
      }
    float mu[4], rs[4];
#pragma unroll
    for (int reg = 0; reg < 4; ++reg) {
      mu[reg] = s1v[reg] * (1.0f / NFn);
      float var = s2v[reg] * (1.0f / NFn) - mu[reg] * mu[reg];
      rs[reg] = rsqrtf(var + LN_EPSn);
    }
#pragma unroll
    for (int c = 0; c < 8; ++c)
#pragma unroll
      for (int reg = 0; reg < 4; ++reg) {
        if (v4[reg]) {
          float feat = (acc[rt][c][reg] - mu[reg]) * rs[reg] * g_r[c] + be_r[c];
          atomicAdd(Nacc + (size_t)s4[reg] * NFn + c * 16 + colb, feat * w4[reg]);
        }
      }
  }
}

__global__ void div_kernel(float* __restrict__ out, const float* __restrict__ D) {
  int i = blockIdx.x * 256 + threadIdx.x;
  if (i < RAn * NFn) {
    float d = D[i >> 7];
    out[i] = (d > 0.f) ? out[i] / d : 0.f;
  }
}

extern "C" void kernel_launch(void* const* d_in, const int* in_sizes, int n_in,
                              void* d_out, int out_size, void* d_ws, size_t ws_size,
                              hipStream_t stream) {
  const float* X = (const float*)d_in[0];
  const float* Wf = (const float*)d_in[1];
  const float* bfeat = (const float*)d_in[2];
  const float* gamma = (const float*)d_in[3];
  const float* beta = (const float*)d_in[4];
  const float* Wa = (const float*)d_in[5];
  const float* ba = (const float*)d_in[6];
  const int* ri = (const int*)d_in[7];
  float* out = (float*)d_out;

  char* ws = (char*)d_ws;
  short* frag = (short*)ws;              // 65,536 B
  int* hist = (int*)(ws + 65536);        // 200,000 B
  int* T = (int*)(ws + 265536);          // 200,000 B
  int* bsum = (int*)(ws + 465536);       // 784 B
  int* boff = (int*)(ws + 466320);       // 784 B
  int* rowstart = (int*)(ws + 467104);   // 200,004 B
  int* cursor = (int*)(ws + 667108);     // 200,000 B
  int* perm = (int*)(ws + 867108);       // 2,000,000 B
  const size_t NEED = 2867108ULL;        // ~2.9 MB

  prep_kernel<<<16, 256, 0, stream>>>(Wf, frag);
  hipMemsetAsync(out, 0, (size_t)RAn * NFn * sizeof(float), stream);

  if (ws_size >= NEED) {
    hipMemsetAsync(hist, 0, (size_t)RAn * sizeof(int), stream);
    hist_kernel<<<(RFn + 255) / 256, 256, 0, stream>>>(ri, hist);
    scanA_kernel<<<SCG, 256, 0, stream>>>(hist, T, bsum);
    scanB_kernel<<<1, 256, 0, stream>>>(bsum, boff);
    scanC_kernel<<<SCG, 256, 0, stream>>>(T, boff, rowstart, cursor);
    scatter_kernel<<<(RFn + 255) / 256, 256, 0, stream>>>(ri, cursor, perm);
    fused2_kernel<<<NBLK2, 256, 0, stream>>>(X, frag, Wa, ba, bfeat, gamma,
                                             beta, rowstart, perm, out);
  } else {
    float* D = (float*)(ws + 65536);
    hipMemsetAsync(D, 0, (size_t)RAn * sizeof(float), stream);
    main_atomic<<<(RFn + 127) / 128, 256, 0, stream>>>(X, frag, Wa, ba, bfeat,
                                                       gamma, beta, ri, out, D);
    div_kernel<<<(RAn * NFn + 255) / 256, 256, 0, stream>>>(out, D);
  }
}

// Round 14
// 308.705 us; speedup vs baseline: 1.7461x; 1.7461x over previous
//
#include <hip/hip_runtime.h>
#include <hip/hip_bf16.h>

#define RFn 500000
#define F1n 256
#define NFn 128
#define RAn 50000
#define LN_EPSn 1e-5f
#define RECB 256          // record: 128 bf16 = 2 full cache lines, 256B-aligned
#define NTILE (RFn / 16)  // 31250 (RFn % 16 == 0: all tiles full)
#define ROWPAD 1040       // LDS bytes per X row (1024 + 16 -> 2-way banks, free)
#define SCB 256
#define SCG ((RAn + SCB - 1) / SCB)  // 196

typedef float f32x4 __attribute__((ext_vector_type(4)));
typedef short short8 __attribute__((ext_vector_type(8)));

__device__ __forceinline__ short f2bf(float f) {
  __hip_bfloat16 h = __float2bfloat16(f);  // RNE
  return __builtin_bit_cast(short, h);
}

__device__ __forceinline__ void gload_lds16(const void* g, void* l) {
  __builtin_amdgcn_global_load_lds(
      (const __attribute__((address_space(1))) void*)g,
      (__attribute__((address_space(3))) void*)l, 16, 0, 0);
}

// ---------------------------------------------------------------------------
// Pack W_feat (256x128 f32) into MFMA B-frag image: frag (s,c), lane l:
// col = c*16+(l&15), k = s*32+(l>>4)*8+i  (8 bf16 per lane).
// ---------------------------------------------------------------------------
__global__ void prep_kernel(const float* __restrict__ Wf, short* __restrict__ frag) {
  int p = blockIdx.x * blockDim.x + threadIdx.x;  // 0..4095
  if (p >= 4096) return;
  int f = p >> 6, l = p & 63;
  int s = f >> 3, c = f & 7;
  int col = c * 16 + (l & 15);
  int k0 = s * 32 + ((l >> 4) << 3);
  short8 v;
#pragma unroll
  for (int i = 0; i < 8; ++i) v[i] = f2bf(Wf[(k0 + i) * NFn + col]);
  *(short8*)(frag + (size_t)p * 8) = v;
}

__global__ void hist_kernel(const int* __restrict__ ri, int* __restrict__ hist) {
  int i = blockIdx.x * 256 + threadIdx.x;
  if (i < RFn) atomicAdd(&hist[ri[i]], 1);
}

__global__ __launch_bounds__(256) void scanA_kernel(const int* __restrict__ hist,
                                                    int* __restrict__ T,
                                                    int* __restrict__ bsum) {
  __shared__ int ls[256];
  const int t = threadIdx.x, idx = blockIdx.x * 256 + t;
  const int v = (idx < RAn) ? hist[idx] : 0;
  ls[t] = v;
  __syncthreads();
  for (int off = 1; off < 256; off <<= 1) {
    int add = (t >= off) ? ls[t - off] : 0;
    __syncthreads();
    ls[t] += add;
    __syncthreads();
  }
  if (idx < RAn) T[idx] = ls[t] - v;
  if (t == 255) bsum[blockIdx.x] = ls[255];
}

__global__ __launch_bounds__(256) void scanB_kernel(int* __restrict__ bsum,
                                                    int* __restrict__ boff) {
  __shared__ int ls[256];
  const int t = threadIdx.x;
  const int v = (t < SCG) ? bsum[t] : 0;
  ls[t] = v;
  __syncthreads();
  for (int off = 1; off < 256; off <<= 1) {
    int add = (t >= off) ? ls[t - off] : 0;
    __syncthreads();
    ls[t] += add;
    __syncthreads();
  }
  if (t < SCG) boff[t] = ls[t] - v;
}

__global__ __launch_bounds__(256) void scanC_kernel(const int* __restrict__ T,
                                                    const int* __restrict__ boff,
                                                    int* __restrict__ rowstart,
                                                    int* __restrict__ cursor) {
  const int idx = blockIdx.x * 256 + threadIdx.x;
  if (idx < RAn) {
    int v = T[idx] + boff[blockIdx.x];
    rowstart[idx] = v;
    cursor[idx] = v;
  }
  if (idx == 0) rowstart[RAn] = RFn;
}

// inv[i] = sorted position of original row i (segment-major order)
__global__ void scatter_kernel(const int* __restrict__ ri, int* __restrict__ cursor,
                               int* __restrict__ inv) {
  int i = blockIdx.x * 256 + threadIdx.x;
  if (i < RFn) inv[i] = atomicAdd(&cursor[ri[i]], 1);
}

// ---------------------------------------------------------------------------
// featw4: one 16-row tile per 128-thr block (2 waves). Single 16.6KB LDS
// buffer -> 9 blocks/CU = 18 waves/CU: cross-block TLP hides staging latency
// (replaces r4's double-buffer at 1/4 the LDS). Waves split output cols
// 64/64 (halves per-wave B-frag L2 traffic + epilogue VALU). LN stats
// exchanged via tiny LDS array. Records: clean 256B-aligned stores at
// sorted positions + separate wbuf (r5-verified format).
// ---------------------------------------------------------------------------
__global__ __launch_bounds__(128) void featw4_kernel(
    const float* __restrict__ X, const short* __restrict__ fragWS,
    const float* __restrict__ Wa, const float* __restrict__ ba,
    const float* __restrict__ bfeat, const float* __restrict__ gamma,
    const float* __restrict__ beta, const int* __restrict__ inv,
    char* __restrict__ buf, float* __restrict__ wbuf) {
  __shared__ __attribute__((aligned(16))) char lt[16 * ROWPAD];  // 16640 B
  __shared__ float sLN[2][16][2];                                // 256 B

  const int tid = threadIdx.x;
  const int lane = tid & 63;
  const int wv = tid >> 6;     // wave: col half (and row half for stage/store)
  const int colb = lane & 15;  // row-in-tile for compute
  const int kg = lane >> 4;
  const int t = blockIdx.x;    // tile: rows t*16 .. t*16+15 (always full)

  // -------- stage my 8 rows (async, no VGPR round-trip) --------
  {
    const float* xr = X + (size_t)t * 16 * F1n;
#pragma unroll
    for (int r = 0; r < 8; ++r) {
      const int rr = wv * 8 + r;
      gload_lds16(xr + rr * F1n + lane * 4, &lt[rr * ROWPAD]);
    }
  }

  // per-lane coefs for my col half: c = wv*4+cc, col = c*16+colb
  float g_r[4], be_r[4], bi_r[4];
#pragma unroll
  for (int cc = 0; cc < 4; ++cc) {
    const int col = (wv * 4 + cc) * 16 + colb;
    g_r[cc] = gamma[col];
    be_r[cc] = beta[col];
    bi_r[cc] = bfeat[col];
  }
  const float batn = ba[0];

  __syncthreads();  // [A] staging complete (drains vmcnt for both waves)

  // -------- GEMM over K=256 (my 4 col-tiles; B-frags from L2) --------
  f32x4 acc[4];
#pragma unroll
  for (int cc = 0; cc < 4; ++cc) acc[cc] = (f32x4)(0.0f);
  float logit = 0.f;

#pragma unroll
  for (int s = 0; s < 8; ++s) {
    short8 bfr[4];
#pragma unroll
    for (int cc = 0; cc < 4; ++cc)
      bfr[cc] = *(const short8*)(fragWS + (((s * 8 + wv * 4 + cc) * 64 + lane) * 8));
    const float4 wa0 = *(const float4*)(Wa + s * 32 + kg * 8);
    const float4 wa1 = *(const float4*)(Wa + s * 32 + kg * 8 + 4);
    const float4 x0 = *(const float4*)(lt + colb * ROWPAD + s * 128 + kg * 32);
    const float4 x1 = *(const float4*)(lt + colb * ROWPAD + s * 128 + kg * 32 + 16);
    float a0 = fmaxf(x0.x, 0.01f * x0.x);
    float a1 = fmaxf(x0.y, 0.01f * x0.y);
    float a2 = fmaxf(x0.z, 0.01f * x0.z);
    float a3 = fmaxf(x0.w, 0.01f * x0.w);
    float a4 = fmaxf(x1.x, 0.01f * x1.x);
    float a5 = fmaxf(x1.y, 0.01f * x1.y);
    float a6 = fmaxf(x1.z, 0.01f * x1.z);
    float a7 = fmaxf(x1.w, 0.01f * x1.w);
    logit += a0 * wa0.x + a1 * wa0.y + a2 * wa0.z + a3 * wa0.w +
             a4 * wa1.x + a5 * wa1.y + a6 * wa1.z + a7 * wa1.w;
    short8 af;
    af[0] = f2bf(a0); af[1] = f2bf(a1); af[2] = f2bf(a2); af[3] = f2bf(a3);
    af[4] = f2bf(a4); af[5] = f2bf(a5); af[6] = f2bf(a6); af[7] = f2bf(a7);
#pragma unroll
    for (int cc = 0; cc < 4; ++cc)
      acc[cc] = __builtin_amdgcn_mfma_f32_16x16x32_bf16(af, bfr[cc], acc[cc], 0, 0, 0);
  }

  // -------- logit -> wexp (rows; both waves compute identically) --------
  float lg = logit;
  lg += __shfl_xor(lg, 16);
  lg += __shfl_xor(lg, 32);
  const float wexp = __expf(lg + batn);
  if (wv == 0 && lane < 16) wbuf[inv[t * 16 + colb]] = wexp;

  // -------- LN partials over my 64 cols (bias included) --------
  float s1v[4] = {0.f, 0.f, 0.f, 0.f}, s2v[4] = {0.f, 0.f, 0.f, 0.f};
#pragma unroll
  for (int cc = 0; cc < 4; ++cc)
#pragma unroll
    for (int reg = 0; reg < 4; ++reg) {
      const float v = acc[cc][reg] + bi_r[cc];
      acc[cc][reg] = v;
      s1v[reg] += v;
      s2v[reg] += v * v;
    }
#pragma unroll
  for (int off = 1; off <= 8; off <<= 1)
#pragma unroll
    for (int reg = 0; reg < 4; ++reg) {
      s1v[reg] += __shfl_xor(s1v[reg], off);
      s2v[reg] += __shfl_xor(s2v[reg], off);
    }
  if (colb == 0) {
#pragma unroll
    for (int reg = 0; reg < 4; ++reg) {
      sLN[wv][kg * 4 + reg][0] = s1v[reg];
      sLN[wv][kg * 4 + reg][1] = s2v[reg];
    }
  }
  __syncthreads();  // [B] partials ready; partner done reading X from lt

  float w4[4];
#pragma unroll
  for (int reg = 0; reg < 4; ++reg) w4[reg] = __shfl(wexp, kg * 4 + reg);

  // -------- finish LN, write feat*w record image into dead lt --------
#pragma unroll
  for (int reg = 0; reg < 4; ++reg) {
    const int row = kg * 4 + reg;
    const float s1 = s1v[reg] + sLN[wv ^ 1][row][0];
    const float s2 = s2v[reg] + sLN[wv ^ 1][row][1];
    const float mu = s1 * (1.0f / NFn);
    const float var = s2 * (1.0f / NFn) - mu * mu;
    const float rs = rsqrtf(var + LN_EPSn);
#pragma unroll
    for (int cc = 0; cc < 4; ++cc) {
      const float feat = (acc[cc][reg] - mu) * rs * g_r[cc] + be_r[cc];
      ((short*)lt)[row * (RECB / 2 + 8) + (wv * 4 + cc) * 16 + colb] =
          f2bf(feat * w4[reg]);  // 272B row stride in LDS (bank spread)
    }
  }
  __syncthreads();  // [C] full records ready

  // -------- 256B-aligned record stores (8 lanes x 32B per row) --------
  {
    const int row = wv * 8 + (lane >> 3);
    const int p = lane & 7;
    const int pos = inv[t * 16 + row];
    const char* src = lt + row * 272 + p * 32;
    char* dst = buf + (size_t)pos * RECB + p * 32;
    int4 v0 = *(const int4*)(src);
    int4 v1 = *(const int4*)(src + 16);
    *(int4*)(dst) = v0;
    *(int4*)(dst + 16) = v1;
  }
}

// ---------------------------------------------------------------------------
// reduce: one wave per segment; 256B records + compact wbuf. Writes every
// segment (zeros for empty) so no out-memset is needed.
// ---------------------------------------------------------------------------
__global__ __launch_bounds__(256) void reduce_kernel(
    const char* __restrict__ buf, const float* __restrict__ wbuf,
    const int* __restrict__ rowstart, float* __restrict__ out) {
  const int lane = threadIdx.x & 63;
  const int seg = blockIdx.x * 4 + (threadIdx.x >> 6);
  if (seg >= RAn) return;
  const int rb = rowstart[seg], re = rowstart[seg + 1];
  float a0 = 0.f, a1 = 0.f, wsum = 0.f;
  for (int p = rb; p < re; ++p) {
    const char* rec = buf + (size_t)p * RECB;
    unsigned v = *(const unsigned*)(rec + lane * 4);
    a0 += __builtin_bit_cast(float, v << 16);
    a1 += __builtin_bit_cast(float, v & 0xffff0000u);
    wsum += wbuf[p];
  }
  float2 o;
  if (re > rb) {
    o.x = a0 / wsum;
    o.y = a1 / wsum;
  } else {
    o.x = 0.f;
    o.y = 0.f;
  }
  *(float2*)(out + (size_t)seg * NFn + lane * 2) = o;
}

// ---------------------------------------------------------------------------
// Fallback path (small ws): round-1 atomic kernel, known-good.
// ---------------------------------------------------------------------------
__global__ __launch_bounds__(256) void main_atomic(
    const float* __restrict__ X, const short* __restrict__ fragWS,
    const float* __restrict__ Wa, const float* __restrict__ ba,
    const float* __restrict__ bfeat, const float* __restrict__ gamma,
    const float* __restrict__ beta, const int* __restrict__ res_index,
    float* __restrict__ Nacc, float* __restrict__ D) {
  __shared__ short sB[4096 * 8];
  const int tid = threadIdx.x;
  {
    const int4* src = (const int4*)fragWS;
    int4* dst = (int4*)sB;
#pragma unroll 4
    for (int i = tid; i < 4096; i += 256) dst[i] = src[i];
  }
  __syncthreads();
  const int lane = tid & 63;
  const int wv = tid >> 6;
  const int rowbase = blockIdx.x * 128 + wv * 32;
  const int colb = lane & 15;
  const int kg = lane >> 4;
  float g_r[8], be_r[8], bi_r[8];
#pragma unroll
  for (int c = 0; c < 8; ++c) {
    int col = c * 16 + colb;
    g_r[c] = gamma[col];
    be_r[c] = beta[col];
    bi_r[c] = bfeat[col];
  }
  const float batn = ba[0];
  f32x4 acc[2][8];
#pragma unroll
  for (int rt = 0; rt < 2; ++rt)
#pragma unroll
    for (int c = 0; c < 8; ++c) acc[rt][c] = (f32x4)(0.0f);
  float logit[2] = {0.f, 0.f};
  int gr0 = rowbase + colb;
  int gr1 = gr0 + 16;
  long r0 = (gr0 < RFn) ? gr0 : (RFn - 1);
  long r1 = (gr1 < RFn) ? gr1 : (RFn - 1);
  const float* xp0 = X + r0 * F1n + kg * 8;
  const float* xp1 = X + r1 * F1n + kg * 8;
#pragma unroll
  for (int s = 0; s < 8; ++s) {
    short8 bfr[8];
#pragma unroll
    for (int c = 0; c < 8; ++c)
      bfr[c] = *(const short8*)(sB + (((s * 8 + c) * 64 + lane) * 8));
    const float4 wa0 = *(const float4*)(Wa + s * 32 + kg * 8);
    const float4 wa1 = *(const float4*)(Wa + s * 32 + kg * 8 + 4);
#pragma unroll
    for (int rt = 0; rt < 2; ++rt) {
      const float* xp = rt ? xp1 : xp0;
      const float4 x0 = *(const float4*)(xp + s * 32);
      const float4 x1 = *(const float4*)(xp + s * 32 + 4);
      float a0 = fmaxf(x0.x, 0.01f * x0.x);
      float a1 = fmaxf(x0.y, 0.01f * x0.y);
      float a2 = fmaxf(x0.z, 0.01f * x0.z);
      float a3 = fmaxf(x0.w, 0.01f * x0.w);
      float a4 = fmaxf(x1.x, 0.01f * x1.x);
      float a5 = fmaxf(x1.y, 0.01f * x1.y);
      float a6 = fmaxf(x1.z, 0.01f * x1.z);
      float a7 = fmaxf(x1.w, 0.01f * x1.w);
      logit[rt] += a0 * wa0.x + a1 * wa0.y + a2 * wa0.z + a3 * wa0.w +
                   a4 * wa1.x + a5 * wa1.y + a6 * wa1.z + a7 * wa1.w;
      short8 af;
      af[0] = f2bf(a0); af[1] = f2bf(a1); af[2] = f2bf(a2); af[3] = f2bf(a3);
      af[4] = f2bf(a4); af[5] = f2bf(a5); af[6] = f2bf(a6); af[7] = f2bf(a7);
#pragma unroll
      for (int c = 0; c < 8; ++c)
        acc[rt][c] = __builtin_amdgcn_mfma_f32_16x16x32_bf16(af, bfr[c],
                                                             acc[rt][c], 0, 0, 0);
    }
  }
#pragma unroll
  for (int rt = 0; rt < 2; ++rt) {
    float lg = logit[rt];
    lg += __shfl_xor(lg, 16);
    lg += __shfl_xor(lg, 32);
    const float wexp = __expf(lg + batn);
    const int gr = rowbase + rt * 16 + colb;
    const int seg = res_index[(gr < RFn) ? gr : (RFn - 1)];
    if (lane < 16 && gr < RFn) atomicAdd(&D[seg], wexp);
    float w4[4];
    int s4[4], v4[4];
#pragma unroll
    for (int reg = 0; reg < 4; ++reg) {
      int srcl = kg * 4 + reg;
      w4[reg] = __shfl(wexp, srcl);
      s4[reg] = __shfl(seg, srcl);
      v4[reg] = (rowbase + rt * 16 + srcl) < RFn;
    }
    float s1v[4] = {0.f, 0.f, 0.f, 0.f}, s2v[4] = {0.f, 0.f, 0.f, 0.f};
#pragma unroll
    for (int c = 0; c < 8; ++c)
#pragma unroll
      for (int reg = 0; reg < 4; ++reg) {
        float t2 = acc[rt][c][reg] + bi_r[c];
        acc[rt][c][reg] = t2;
        s1v[reg] += t2;
        s2v[reg] += t2 * t2;
      }
#pragma unroll
    for (int off = 1; off <= 8; off <<= 1)
#pragma unroll
      for (int reg = 0; reg < 4; ++reg) {
        s1v[reg] += __shfl_xor(s1v[reg], off);
        s2v[reg] += __shfl_xor(s2v[reg], off);
      }
    float mu[4], rs[4];
#pragma unroll
    for (int reg = 0; reg < 4; ++reg) {
      mu[reg] = s1v[reg] * (1.0f / NFn);
      float var = s2v[reg] * (1.0f / NFn) - mu[reg] * mu[reg];
      rs[reg] = rsqrtf(var + LN_EPSn);
    }
#pragma unroll
    for (int c = 0; c < 8; ++c)
#pragma unroll
      for (int reg = 0; reg < 4; ++reg) {
        if (v4[reg]) {
          float feat = (acc[rt][c][reg] - mu[reg]) * rs[reg] * g_r[c] + be_r[c];
          atomicAdd(Nacc + (size_t)s4[reg] * NFn + c * 16 + colb, feat * w4[reg]);
        }
      }
  }
}

__global__ void div_kernel(float* __restrict__ out, const float* __restrict__ D) {
  int i = blockIdx.x * 256 + threadIdx.x;
  if (i < RAn * NFn) {
    float d = D[i >> 7];
    out[i] = (d > 0.f) ? out[i] / d : 0.f;
  }
}

extern "C" void kernel_launch(void* const* d_in, const int* in_sizes, int n_in,
                              void* d_out, int out_size, void* d_ws, size_t ws_size,
                              hipStream_t stream) {
  const float* X = (const float*)d_in[0];
  const float* Wf = (const float*)d_in[1];
  const float* bfeat = (const float*)d_in[2];
  const float* gamma = (const float*)d_in[3];
  const float* beta = (const float*)d_in[4];
  const float* Wa = (const float*)d_in[5];
  const float* ba = (const float*)d_in[6];
  const int* ri = (const int*)d_in[7];
  float* out = (float*)d_out;

  char* ws = (char*)d_ws;
  short* frag = (short*)ws;              // 65,536 B
  int* hist = (int*)(ws + 65536);        // 200,000 B
  int* T = (int*)(ws + 265536);          // 200,000 B
  int* bsum = (int*)(ws + 465536);       // 784 B
  int* boff = (int*)(ws + 466320);       // 784 B
  int* rowstart = (int*)(ws + 467104);   // 200,004 B
  int* cursor = (int*)(ws + 667108);     // 200,000 B
  int* inv = (int*)(ws + 867108);        // 2,000,000 B
  float* wbuf = (float*)(ws + 2867108);  // 2,000,000 B
  char* buf = ws + 4867328;              // 256-aligned; 128,000,000 B
  const size_t NEED = 4867328ULL + (size_t)RFn * RECB;  // ~132.9 MB

  prep_kernel<<<16, 256, 0, stream>>>(Wf, frag);

  if (ws_size >= NEED) {
    hipMemsetAsync(hist, 0, (size_t)RAn * sizeof(int), stream);
    hist_kernel<<<(RFn + 255) / 256, 256, 0, stream>>>(ri, hist);
    scanA_kernel<<<SCG, 256, 0, stream>>>(hist, T, bsum);
    scanB_kernel<<<1, 256, 0, stream>>>(bsum, boff);
    scanC_kernel<<<SCG, 256, 0, stream>>>(T, boff, rowstart, cursor);
    scatter_kernel<<<(RFn + 255) / 256, 256, 0, stream>>>(ri, cursor, inv);
    featw4_kernel<<<NTILE, 128, 0, stream>>>(X, frag, Wa, ba, bfeat, gamma,
                                             beta, inv, buf, wbuf);
    reduce_kernel<<<(RAn + 3) / 4, 256, 0, stream>>>(buf, wbuf, rowstart, out);
  } else {
    float* D = (float*)(ws + 65536);
    hipMemsetAsync(out, 0, (size_t)RAn * NFn * sizeof(float), stream);
    hipMemsetAsync(D, 0, (size_t)RAn * sizeof(float), stream);
    main_atomic<<<(RFn + 127) / 128, 256, 0, stream>>>(X, frag, Wa, ba, bfeat,
                                                       gamma, beta, ri, out, D);
    div_kernel<<<(RAn * NFn + 255) / 256, 256, 0, stream>>>(out, D);
  }
}

// Round 15
// 295.907 us; speedup vs baseline: 1.8216x; 1.0432x over previous
//
#include <hip/hip_runtime.h>
#include <hip/hip_bf16.h>

#define RFn 500000
#define F1n 256
#define NFn 128
#define RAn 50000
#define LN_EPSn 1e-5f
#define RECB 256          // record: 128 bf16 = 2 full cache lines, 256B-aligned
#define NTILE2 (RFn / 32) // 15625 32-row blocks (RFn % 32 == 0: all full)
#define ROWPAD 1040       // LDS bytes per X row (1024 + 16 -> 2-way banks, free)
#define SCB 256
#define SCG ((RAn + SCB - 1) / SCB)  // 196

typedef float f32x4 __attribute__((ext_vector_type(4)));
typedef short short8 __attribute__((ext_vector_type(8)));

__device__ __forceinline__ short f2bf(float f) {
  __hip_bfloat16 h = __float2bfloat16(f);  // RNE
  return __builtin_bit_cast(short, h);
}

__device__ __forceinline__ void gload_lds16(const void* g, void* l) {
  __builtin_amdgcn_global_load_lds(
      (const __attribute__((address_space(1))) void*)g,
      (__attribute__((address_space(3))) void*)l, 16, 0, 0);
}

// ---------------------------------------------------------------------------
// Pack W_feat (256x128 f32) into MFMA B-frag image: frag (s,c), lane l:
// col = c*16+(l&15), k = s*32+(l>>4)*8+i  (8 bf16 per lane).
// ---------------------------------------------------------------------------
__global__ void prep_kernel(const float* __restrict__ Wf, short* __restrict__ frag) {
  int p = blockIdx.x * blockDim.x + threadIdx.x;  // 0..4095
  if (p >= 4096) return;
  int f = p >> 6, l = p & 63;
  int s = f >> 3, c = f & 7;
  int col = c * 16 + (l & 15);
  int k0 = s * 32 + ((l >> 4) << 3);
  short8 v;
#pragma unroll
  for (int i = 0; i < 8; ++i) v[i] = f2bf(Wf[(k0 + i) * NFn + col]);
  *(short8*)(frag + (size_t)p * 8) = v;
}

__global__ void hist_kernel(const int* __restrict__ ri, int* __restrict__ hist) {
  int i = blockIdx.x * 256 + threadIdx.x;
  if (i < RFn) atomicAdd(&hist[ri[i]], 1);
}

__global__ __launch_bounds__(256) void scanA_kernel(const int* __restrict__ hist,
                                                    int* __restrict__ T,
                                                    int* __restrict__ bsum) {
  __shared__ int ls[256];
  const int t = threadIdx.x, idx = blockIdx.x * 256 + t;
  const int v = (idx < RAn) ? hist[idx] : 0;
  ls[t] = v;
  __syncthreads();
  for (int off = 1; off < 256; off <<= 1) {
    int add = (t >= off) ? ls[t - off] : 0;
    __syncthreads();
    ls[t] += add;
    __syncthreads();
  }
  if (idx < RAn) T[idx] = ls[t] - v;
  if (t == 255) bsum[blockIdx.x] = ls[255];
}

__global__ __launch_bounds__(256) void scanB_kernel(int* __restrict__ bsum,
                                                    int* __restrict__ boff) {
  __shared__ int ls[256];
  const int t = threadIdx.x;
  const int v = (t < SCG) ? bsum[t] : 0;
  ls[t] = v;
  __syncthreads();
  for (int off = 1; off < 256; off <<= 1) {
    int add = (t >= off) ? ls[t - off] : 0;
    __syncthreads();
    ls[t] += add;
    __syncthreads();
  }
  if (t < SCG) boff[t] = ls[t] - v;
}

__global__ __launch_bounds__(256) void scanC_kernel(const int* __restrict__ T,
                                                    const int* __restrict__ boff,
                                                    int* __restrict__ rowstart,
                                                    int* __restrict__ cursor) {
  const int idx = blockIdx.x * 256 + threadIdx.x;
  if (idx < RAn) {
    int v = T[idx] + boff[blockIdx.x];
    rowstart[idx] = v;
    cursor[idx] = v;
  }
  if (idx == 0) rowstart[RAn] = RFn;
}

// inv[i] = sorted position of original row i (segment-major order)
__global__ void scatter_kernel(const int* __restrict__ ri, int* __restrict__ cursor,
                               int* __restrict__ inv) {
  int i = blockIdx.x * 256 + threadIdx.x;
  if (i < RFn) inv[i] = atomicAdd(&cursor[ri[i]], 1);
}

// ---------------------------------------------------------------------------
// featw5: 32-row block, 128 thr (2 waves). Col-split 64/64 across waves
// (r14) PLUS 2 row-tiles per block sharing each B-frag load (r1's rt loop):
// B L2 traffic halves to ~1GB. Single 33KB LDS buffer -> 4 blocks/CU =
// 8 waves/CU; async global_load_lds staging, cross-block overlap. LN stats
// via sLN exchange. Records: clean 256B-aligned stores + wbuf (r5 format).
// ---------------------------------------------------------------------------
__global__ __launch_bounds__(128) void featw5_kernel(
    const float* __restrict__ X, const short* __restrict__ fragWS,
    const float* __restrict__ Wa, const float* __restrict__ ba,
    const float* __restrict__ bfeat, const float* __restrict__ gamma,
    const float* __restrict__ beta, const int* __restrict__ inv,
    char* __restrict__ buf, float* __restrict__ wbuf) {
  __shared__ __attribute__((aligned(16))) char lt[32 * ROWPAD];  // 33280 B
  __shared__ float sLN[2][32][2];                                // 512 B

  const int tid = threadIdx.x;
  const int lane = tid & 63;
  const int wv = tid >> 6;     // wave = col half
  const int colb = lane & 15;  // row-in-row-tile for compute
  const int kg = lane >> 4;
  const int t = blockIdx.x;    // rows t*32 .. t*32+31 (always full)

  // -------- stage my 16 rows (async, no VGPR round-trip) --------
  {
    const float* xr = X + (size_t)t * 32 * F1n;
#pragma unroll
    for (int r = 0; r < 16; ++r) {
      const int rr = wv * 16 + r;
      gload_lds16(xr + rr * F1n + lane * 4, &lt[rr * ROWPAD]);
    }
  }

  // per-lane coefs for my col half: ct = wv*4+cc, col = ct*16+colb
  float g_r[4], be_r[4], bi_r[4];
#pragma unroll
  for (int cc = 0; cc < 4; ++cc) {
    const int col = (wv * 4 + cc) * 16 + colb;
    g_r[cc] = gamma[col];
    be_r[cc] = beta[col];
    bi_r[cc] = bfeat[col];
  }
  const float batn = ba[0];

  __syncthreads();  // [A] staging complete for both waves

  // -------- GEMM over K=256: 4 col-tiles x 2 row-tiles, shared bfr --------
  f32x4 acc[2][4];
#pragma unroll
  for (int rt = 0; rt < 2; ++rt)
#pragma unroll
    for (int cc = 0; cc < 4; ++cc) acc[rt][cc] = (f32x4)(0.0f);
  float logit[2] = {0.f, 0.f};

#pragma unroll
  for (int s = 0; s < 8; ++s) {
    short8 bfr[4];
#pragma unroll
    for (int cc = 0; cc < 4; ++cc)
      bfr[cc] = *(const short8*)(fragWS + (((s * 8 + wv * 4 + cc) * 64 + lane) * 8));
    const float4 wa0 = *(const float4*)(Wa + s * 32 + kg * 8);
    const float4 wa1 = *(const float4*)(Wa + s * 32 + kg * 8 + 4);
#pragma unroll
    for (int rt = 0; rt < 2; ++rt) {
      const char* xrow = lt + (rt * 16 + colb) * ROWPAD + s * 128 + kg * 32;
      const float4 x0 = *(const float4*)(xrow);
      const float4 x1 = *(const float4*)(xrow + 16);
      float a0 = fmaxf(x0.x, 0.01f * x0.x);
      float a1 = fmaxf(x0.y, 0.01f * x0.y);
      float a2 = fmaxf(x0.z, 0.01f * x0.z);
      float a3 = fmaxf(x0.w, 0.01f * x0.w);
      float a4 = fmaxf(x1.x, 0.01f * x1.x);
      float a5 = fmaxf(x1.y, 0.01f * x1.y);
      float a6 = fmaxf(x1.z, 0.01f * x1.z);
      float a7 = fmaxf(x1.w, 0.01f * x1.w);
      logit[rt] += a0 * wa0.x + a1 * wa0.y + a2 * wa0.z + a3 * wa0.w +
                   a4 * wa1.x + a5 * wa1.y + a6 * wa1.z + a7 * wa1.w;
      short8 af;
      af[0] = f2bf(a0); af[1] = f2bf(a1); af[2] = f2bf(a2); af[3] = f2bf(a3);
      af[4] = f2bf(a4); af[5] = f2bf(a5); af[6] = f2bf(a6); af[7] = f2bf(a7);
#pragma unroll
      for (int cc = 0; cc < 4; ++cc)
        acc[rt][cc] =
            __builtin_amdgcn_mfma_f32_16x16x32_bf16(af, bfr[cc], acc[rt][cc], 0, 0, 0);
    }
  }

  // -------- per row-tile: wexp, LN partials --------
  float wexp[2];
  float s1v[2][4], s2v[2][4];
#pragma unroll
  for (int rt = 0; rt < 2; ++rt) {
    float lg = logit[rt];
    lg += __shfl_xor(lg, 16);
    lg += __shfl_xor(lg, 32);
    wexp[rt] = __expf(lg + batn);
    if (wv == 0 && lane < 16) wbuf[inv[t * 32 + rt * 16 + colb]] = wexp[rt];

#pragma unroll
    for (int reg = 0; reg < 4; ++reg) {
      s1v[rt][reg] = 0.f;
      s2v[rt][reg] = 0.f;
    }
#pragma unroll
    for (int cc = 0; cc < 4; ++cc)
#pragma unroll
      for (int reg = 0; reg < 4; ++reg) {
        const float v = acc[rt][cc][reg] + bi_r[cc];
        acc[rt][cc][reg] = v;
        s1v[rt][reg] += v;
        s2v[rt][reg] += v * v;
      }
#pragma unroll
    for (int off = 1; off <= 8; off <<= 1)
#pragma unroll
      for (int reg = 0; reg < 4; ++reg) {
        s1v[rt][reg] += __shfl_xor(s1v[rt][reg], off);
        s2v[rt][reg] += __shfl_xor(s2v[rt][reg], off);
      }
    if (colb == 0) {
#pragma unroll
      for (int reg = 0; reg < 4; ++reg) {
        sLN[wv][rt * 16 + kg * 4 + reg][0] = s1v[rt][reg];
        sLN[wv][rt * 16 + kg * 4 + reg][1] = s2v[rt][reg];
      }
    }
  }
  __syncthreads();  // [B] partials ready; both waves done reading X from lt

  // -------- finish LN, write feat*w record image into dead lt --------
#pragma unroll
  for (int rt = 0; rt < 2; ++rt) {
    float w4[4];
#pragma unroll
    for (int reg = 0; reg < 4; ++reg) w4[reg] = __shfl(wexp[rt], kg * 4 + reg);
#pragma unroll
    for (int reg = 0; reg < 4; ++reg) {
      const int row = rt * 16 + kg * 4 + reg;
      const float s1 = s1v[rt][reg] + sLN[wv ^ 1][row][0];
      const float s2 = s2v[rt][reg] + sLN[wv ^ 1][row][1];
      const float mu = s1 * (1.0f / NFn);
      const float var = s2 * (1.0f / NFn) - mu * mu;
      const float rs = rsqrtf(var + LN_EPSn);
#pragma unroll
      for (int cc = 0; cc < 4; ++cc) {
        const float feat = (acc[rt][cc][reg] - mu) * rs * g_r[cc] + be_r[cc];
        ((short*)lt)[row * 136 + (wv * 4 + cc) * 16 + colb] =
            f2bf(feat * w4[reg]);  // 272B LDS row stride (bank spread)
      }
    }
  }
  __syncthreads();  // [C] full records ready

  // -------- 256B-aligned record stores (4 lanes x 64B per row) --------
  {
    const int row = tid >> 2;  // 0..31
    const int p = tid & 3;     // 64B chunk pair
    const int pos = inv[t * 32 + row];
    const char* src = lt + row * 272 + p * 64;
    char* dst = buf + (size_t)pos * RECB + p * 64;
    int4 v0 = *(const int4*)(src);
    int4 v1 = *(const int4*)(src + 16);
    int4 v2 = *(const int4*)(src + 32);
    int4 v3 = *(const int4*)(src + 48);
    *(int4*)(dst) = v0;
    *(int4*)(dst + 16) = v1;
    *(int4*)(dst + 32) = v2;
    *(int4*)(dst + 48) = v3;
  }
}

// ---------------------------------------------------------------------------
// reduce: one wave per segment; 256B records + compact wbuf. Writes every
// segment (zeros for empty) so no out-memset is needed.
// ---------------------------------------------------------------------------
__global__ __launch_bounds__(256) void reduce_kernel(
    const char* __restrict__ buf, const float* __restrict__ wbuf,
    const int* __restrict__ rowstart, float* __restrict__ out) {
  const int lane = threadIdx.x & 63;
  const int seg = blockIdx.x * 4 + (threadIdx.x >> 6);
  if (seg >= RAn) return;
  const int rb = rowstart[seg], re = rowstart[seg + 1];
  float a0 = 0.f, a1 = 0.f, wsum = 0.f;
  for (int p = rb; p < re; ++p) {
    const char* rec = buf + (size_t)p * RECB;
    unsigned v = *(const unsigned*)(rec + lane * 4);
    a0 += __builtin_bit_cast(float, v << 16);
    a1 += __builtin_bit_cast(float, v & 0xffff0000u);
    wsum += wbuf[p];
  }
  float2 o;
  if (re > rb) {
    o.x = a0 / wsum;
    o.y = a1 / wsum;
  } else {
    o.x = 0.f;
    o.y = 0.f;
  }
  *(float2*)(out + (size_t)seg * NFn + lane * 2) = o;
}

// ---------------------------------------------------------------------------
// Fallback path (small ws): round-1 atomic kernel, known-good.
// ---------------------------------------------------------------------------
__global__ __launch_bounds__(256) void main_atomic(
    const float* __restrict__ X, const short* __restrict__ fragWS,
    const float* __restrict__ Wa, const float* __restrict__ ba,
    const float* __restrict__ bfeat, const float* __restrict__ gamma,
    const float* __restrict__ beta, const int* __restrict__ res_index,
    float* __restrict__ Nacc, float* __restrict__ D) {
  __shared__ short sB[4096 * 8];
  const int tid = threadIdx.x;
  {
    const int4* src = (const int4*)fragWS;
    int4* dst = (int4*)sB;
#pragma unroll 4
    for (int i = tid; i < 4096; i += 256) dst[i] = src[i];
  }
  __syncthreads();
  const int lane = tid & 63;
  const int wv = tid >> 6;
  const int rowbase = blockIdx.x * 128 + wv * 32;
  const int colb = lane & 15;
  const int kg = lane >> 4;
  float g_r[8], be_r[8], bi_r[8];
#pragma unroll
  for (int c = 0; c < 8; ++c) {
    int col = c * 16 + colb;
    g_r[c] = gamma[col];
    be_r[c] = beta[col];
    bi_r[c] = bfeat[col];
  }
  const float batn = ba[0];
  f32x4 acc[2][8];
#pragma unroll
  for (int rt = 0; rt < 2; ++rt)
#pragma unroll
    for (int c = 0; c < 8; ++c) acc[rt][c] = (f32x4)(0.0f);
  float logit[2] = {0.f, 0.f};
  int gr0 = rowbase + colb;
  int gr1 = gr0 + 16;
  long r0 = (gr0 < RFn) ? gr0 : (RFn - 1);
  long r1 = (gr1 < RFn) ? gr1 : (RFn - 1);
  const float* xp0 = X + r0 * F1n + kg * 8;
  const float* xp1 = X + r1 * F1n + kg * 8;
#pragma unroll
  for (int s = 0; s < 8; ++s) {
    short8 bfr[8];
#pragma unroll
    for (int c = 0; c < 8; ++c)
      bfr[c] = *(const short8*)(sB + (((s * 8 + c) * 64 + lane) * 8));
    const float4 wa0 = *(const float4*)(Wa + s * 32 + kg * 8);
    const float4 wa1 = *(const float4*)(Wa + s * 32 + kg * 8 + 4);
#pragma unroll
    for (int rt = 0; rt < 2; ++rt) {
      const float* xp = rt ? xp1 : xp0;
      const float4 x0 = *(const float4*)(xp + s * 32);
      const float4 x1 = *(const float4*)(xp + s * 32 + 4);
      float a0 = fmaxf(x0.x, 0.01f * x0.x);
      float a1 = fmaxf(x0.y, 0.01f * x0.y);
      float a2 = fmaxf(x0.z, 0.01f * x0.z);
      float a3 = fmaxf(x0.w, 0.01f * x0.w);
      float a4 = fmaxf(x1.x, 0.01f * x1.x);
      float a5 = fmaxf(x1.y, 0.01f * x1.y);
      float a6 = fmaxf(x1.z, 0.01f * x1.z);
      float a7 = fmaxf(x1.w, 0.01f * x1.w);
      logit[rt] += a0 * wa0.x + a1 * wa0.y + a2 * wa0.z + a3 * wa0.w +
                   a4 * wa1.x + a5 * wa1.y + a6 * wa1.z + a7 * wa1.w;
      short8 af;
      af[0] = f2bf(a0); af[1] = f2bf(a1); af[2] = f2bf(a2); af[3] = f2bf(a3);
      af[4] = f2bf(a4); af[5] = f2bf(a5); af[6] = f2bf(a6); af[7] = f2bf(a7);
#pragma unroll
      for (int c = 0; c < 8; ++c)
        acc[rt][c] = __builtin_amdgcn_mfma_f32_16x16x32_bf16(af, bfr[c],
                                                             acc[rt][c], 0, 0, 0);
    }
  }
#pragma unroll
  for (int rt = 0; rt < 2; ++rt) {
    float lg = logit[rt];
    lg += __shfl_xor(lg, 16);
    lg += __shfl_xor(lg, 32);
    const float wexp = __expf(lg + batn);
    const int gr = rowbase + rt * 16 + colb;
    const int seg = res_index[(gr < RFn) ? gr : (RFn - 1)];
    if (lane < 16 && gr < RFn) atomicAdd(&D[seg], wexp);
    float w4[4];
    int s4[4], v4[4];
#pragma unroll
    for (int reg = 0; reg < 4; ++reg) {
      int srcl = kg * 4 + reg;
      w4[reg] = __shfl(wexp, srcl);
      s4[reg] = __shfl(seg, srcl);
      v4[reg] = (rowbase + rt * 16 + srcl) < RFn;
    }
    float s1v[4] = {0.f, 0.f, 0.f, 0.f}, s2v[4] = {0.f, 0.f, 0.f, 0.f};
#pragma unroll
    for (int c = 0; c < 8; ++c)
#pragma unroll
      for (int reg = 0; reg < 4; ++reg) {
        float t2 = acc[rt][c][reg] + bi_r[c];
        acc[rt][c][reg] = t2;
        s1v[reg] += t2;
        s2v[reg] += t2 * t2;
      }
#pragma unroll
    for (int off = 1; off <= 8; off <<= 1)
#pragma unroll
      for (int reg = 0; reg < 4; ++reg) {
        s1v[reg] += __shfl_xor(s1v[reg], off);
        s2v[reg] += __shfl_xor(s2v[reg], off);
      }
    float mu[4], rs[4];
#pragma unroll
    for (int reg = 0; reg < 4; ++reg) {
      mu[reg] = s1v[reg] * (1.0f / NFn);
      float var = s2v[reg] * (1.0f / NFn) - mu[reg] * mu[reg];
      rs[reg] = rsqrtf(var + LN_EPSn);
    }
#pragma unroll
    for (int c = 0; c < 8; ++c)
#pragma unroll
      for (int reg = 0; reg < 4; ++reg) {
        if (v4[reg]) {
          float feat = (acc[rt][c][reg] - mu[reg]) * rs[reg] * g_r[c] + be_r[c];
          atomicAdd(Nacc + (size_t)s4[reg] * NFn + c * 16 + colb, feat * w4[reg]);
        }
      }
  }
}

__global__ void div_kernel(float* __restrict__ out, const float* __restrict__ D) {
  int i = blockIdx.x * 256 + threadIdx.x;
  if (i < RAn * NFn) {
    float d = D[i >> 7];
    out[i] = (d > 0.f) ? out[i] / d : 0.f;
  }
}

extern "C" void kernel_launch(void* const* d_in, const int* in_sizes, int n_in,
                              void* d_out, int out_size, void* d_ws, size_t ws_size,
                              hipStream_t stream) {
  const float* X = (const float*)d_in[0];
  const float* Wf = (const float*)d_in[1];
  const float* bfeat = (const float*)d_in[2];
  const float* gamma = (const float*)d_in[3];
  const float* beta = (const float*)d_in[4];
  const float* Wa = (const float*)d_in[5];
  const float* ba = (const float*)d_in[6];
  const int* ri = (const int*)d_in[7];
  float* out = (float*)d_out;

  char* ws = (char*)d_ws;
  short* frag = (short*)ws;              // 65,536 B
  int* hist = (int*)(ws + 65536);        // 200,000 B
  int* T = (int*)(ws + 265536);          // 200,000 B
  int* bsum = (int*)(ws + 465536);       // 784 B
  int* boff = (int*)(ws + 466320);       // 784 B
  int* rowstart = (int*)(ws + 467104);   // 200,004 B
  int* cursor = (int*)(ws + 667108);     // 200,000 B
  int* inv = (int*)(ws + 867108);        // 2,000,000 B
  float* wbuf = (float*)(ws + 2867108);  // 2,000,000 B
  char* buf = ws + 4867328;              // 256-aligned; 128,000,000 B
  const size_t NEED = 4867328ULL + (size_t)RFn * RECB;  // ~132.9 MB

  prep_kernel<<<16, 256, 0, stream>>>(Wf, frag);

  if (ws_size >= NEED) {
    hipMemsetAsync(hist, 0, (size_t)RAn * sizeof(int), stream);
    hist_kernel<<<(RFn + 255) / 256, 256, 0, stream>>>(ri, hist);
    scanA_kernel<<<SCG, 256, 0, stream>>>(hist, T, bsum);
    scanB_kernel<<<1, 256, 0, stream>>>(bsum, boff);
    scanC_kernel<<<SCG, 256, 0, stream>>>(T, boff, rowstart, cursor);
    scatter_kernel<<<(RFn + 255) / 256, 256, 0, stream>>>(ri, cursor, inv);
    featw5_kernel<<<NTILE2, 128, 0, stream>>>(X, frag, Wa, ba, bfeat, gamma,
                                              beta, inv, buf, wbuf);
    reduce_kernel<<<(RAn + 3) / 4, 256, 0, stream>>>(buf, wbuf, rowstart, out);
  } else {
    float* D = (float*)(ws + 65536);
    hipMemsetAsync(out, 0, (size_t)RAn * NFn * sizeof(float), stream);
    hipMemsetAsync(D, 0, (size_t)RAn * sizeof(float), stream);
    main_atomic<<<(RFn + 127) / 128, 256, 0, stream>>>(X, frag, Wa, ba, bfeat,
                                                       gamma, beta, ri, out, D);
    div_kernel<<<(RAn * NFn + 255) / 256, 256, 0, stream>>>(out, D);
  }
}